// Round 1
// baseline (31585.910 us; speedup 1.0000x reference)
//
#include <hip/hip_runtime.h>

// GRU: B=256, T=512, F=256, H=512, C=10
// Persistent cooperative-style kernel (plain launch, occupancy-guaranteed):
//  - 128 WGs x 256 thr. 4 batch-groups (64 rows) x 32 col-WGs (16 cols).
//  - Weights (3 gates x [768,16]) live in registers as MFMA B-fragments (288 VGPR).
//  - A-operands ([h|x] and [r*h|x]) are loaded global->fragment directly (no LDS).
//  - 2 device-scope barriers per step, scoped to the 32 WGs of a batch group.
//  - blockIdx swizzle: group g lives on XCDs {2g,2g+1} so h/rh/x broadcasts hit L2.

#define BB 256
#define TT 512
#define FF 256
#define HH 512
#define NCOL 32
#define GROUP_WGS 32

typedef short short8 __attribute__((ext_vector_type(8)));
typedef float float4v __attribute__((ext_vector_type(4)));

// ws layout (bytes)
#define WFRAG_OFF 0
#define WFRAG_BYTES (NCOL * 3 * 24 * 64 * 8 * 2)          // 2,359,296
#define HBUF_OFF (WFRAG_OFF + WFRAG_BYTES)                 // bf16 h  [256][512]
#define RHBUF_OFF (HBUF_OFF + BB * HH * 2)                 // bf16 r*h[256][512]
#define HFIN_OFF (RHBUF_OFF + BB * HH * 2)                 // f32 h_final [256][512]
#define BAR_OFF (HFIN_OFF + BB * HH * 4)                   // 4 x 256B counters
#define WS_NEEDED (BAR_OFF + 1024)

__device__ __forceinline__ short f2bf(float f) {
  unsigned u = __builtin_bit_cast(unsigned, f);
  u += 0x7fffu + ((u >> 16) & 1u);            // RNE to bf16 (no NaN in data)
  return (short)(u >> 16);
}
__device__ __forceinline__ float sigm(float v) { return 1.0f / (1.0f + __expf(-v)); }
__device__ __forceinline__ float tanh_(float v) { return 2.0f / (1.0f + __expf(-2.0f * v)) - 1.0f; }

// Build bf16 MFMA B-fragments from f32 weights [768][512].
// Frag (cb, g, kk, lane, j): n = cb*16 + (lane&15), k = kk*32 + (lane>>4)*8 + j.
__global__ void prep_w(const float* __restrict__ Wz, const float* __restrict__ Wr,
                       const float* __restrict__ Wh, short* __restrict__ wfrag) {
  int id = blockIdx.x * 256 + threadIdx.x;     // 576*256 == 32*3*24*64
  int lane = id & 63;
  int rest = id >> 6;                          // (cb*3+g)*24 + kk
  int kk = rest % 24;
  int gc = rest / 24;
  int g = gc % 3;
  int cb = gc / 3;
  if (cb >= NCOL) return;
  const float* W = (g == 0) ? Wz : ((g == 1) ? Wr : Wh);
  int n = cb * 16 + (lane & 15);
  int kbase = kk * 32 + (lane >> 4) * 8;
  short8 v;
#pragma unroll
  for (int j = 0; j < 8; ++j) v[j] = f2bf(W[(size_t)(kbase + j) * HH + n]);
  *(((short8*)wfrag) + id) = v;
}

__device__ __forceinline__ void group_barrier(int* bar, int tgt) {
  __threadfence();           // release: make our global stores agent-visible
  __syncthreads();
  if (threadIdx.x == 0) {
    __hip_atomic_fetch_add(bar, 1, __ATOMIC_RELEASE, __HIP_MEMORY_SCOPE_AGENT);
    while (__hip_atomic_load(bar, __ATOMIC_ACQUIRE, __HIP_MEMORY_SCOPE_AGENT) < tgt)
      __builtin_amdgcn_s_sleep(2);
  }
  __syncthreads();
  __threadfence();           // acquire: invalidate stale cached lines
}

__global__ __launch_bounds__(256, 1) void gru_kernel(
    const float* __restrict__ x, const short* __restrict__ wfrag,
    short* __restrict__ hbuf, short* __restrict__ rhbuf,
    float* __restrict__ hfin, int* __restrict__ bars,
    const float* __restrict__ bzv, const float* __restrict__ brv,
    const float* __restrict__ bhv) {
  const int bid = blockIdx.x;          // 0..127
  const int xcd = bid & 7;             // blockIdx%8 ~ XCD (round-robin dispatch)
  const int group = xcd >> 1;          // batch group 0..3 -> XCD pair
  const int cb = ((bid >> 3) << 1) | (xcd & 1);  // col block 0..31
  const int tid = threadIdx.x;
  const int w = tid >> 6;              // wave 0..3 -> 16-row M tile
  const int l = tid & 63;
  const int l15 = l & 15;
  const int lhi = l >> 4;
  const int rb = group * 64;
  const int jc = cb * 16;

  // ---- weights -> registers (B-fragments), 288 VGPR ----
  const short8* wf = (const short8*)wfrag;
  short8 wz[24], wr[24], wh[24];
#pragma unroll
  for (int kk = 0; kk < 24; ++kk) wz[kk] = wf[((cb * 3 + 0) * 24 + kk) * 64 + l];
#pragma unroll
  for (int kk = 0; kk < 24; ++kk) wr[kk] = wf[((cb * 3 + 1) * 24 + kk) * 64 + l];
#pragma unroll
  for (int kk = 0; kk < 24; ++kk) wh[kk] = wf[((cb * 3 + 2) * 24 + kk) * 64 + l];

  const float bz = bzv[jc + l15], br = brv[jc + l15], bh = bhv[jc + l15];

  const int arow = rb + w * 16 + l15;        // A-fragment row (batch row)
  const int drow = rb + w * 16 + lhi * 4;    // D rows base (+i)
  const int dcol = jc + l15;

  const short* hb_lane = hbuf + (size_t)arow * HH + lhi * 8;
  const short* rh_lane = rhbuf + (size_t)arow * HH + lhi * 8;
  const float* x_lane0 = x + (size_t)arow * TT * FF + lhi * 8;

  float4v h_loc = {0.f, 0.f, 0.f, 0.f};
  int tgt = 0;
  int* bar = bars + group * 64;

  // prefetch x fragments for t=0
  short8 xf[8];
  {
    const float* xl = x_lane0;  // t = 0
#pragma unroll
    for (int kx = 0; kx < 8; ++kx) {
      float4v a = *(const float4v*)(xl + kx * 32);
      float4v b2 = *(const float4v*)(xl + kx * 32 + 4);
      short8 v;
      v[0] = f2bf(a[0]); v[1] = f2bf(a[1]); v[2] = f2bf(a[2]); v[3] = f2bf(a[3]);
      v[4] = f2bf(b2[0]); v[5] = f2bf(b2[1]); v[6] = f2bf(b2[2]); v[7] = f2bf(b2[3]);
      xf[kx] = v;
    }
  }

#pragma unroll 1
  for (int t = 0; t < TT; ++t) {
    // ================= phase 1: z, r =================
    float4v az = {0.f, 0.f, 0.f, 0.f}, ar = {0.f, 0.f, 0.f, 0.f};
#pragma unroll
    for (int kx = 0; kx < 8; ++kx) {   // x part first (covers cold h loads)
      az = __builtin_amdgcn_mfma_f32_16x16x32_bf16(xf[kx], wz[16 + kx], az, 0, 0, 0);
      ar = __builtin_amdgcn_mfma_f32_16x16x32_bf16(xf[kx], wr[16 + kx], ar, 0, 0, 0);
    }
#pragma unroll
    for (int kk = 0; kk < 16; ++kk) {  // h part (K=512)
      short8 a = *(const short8*)(hb_lane + kk * 32);
      az = __builtin_amdgcn_mfma_f32_16x16x32_bf16(a, wz[kk], az, 0, 0, 0);
      ar = __builtin_amdgcn_mfma_f32_16x16x32_bf16(a, wr[kk], ar, 0, 0, 0);
    }
    float4v z, rr;
#pragma unroll
    for (int i = 0; i < 4; ++i) {
      z[i] = sigm(az[i] + bz);
      rr[i] = sigm(ar[i] + br);
    }
#pragma unroll
    for (int i = 0; i < 4; ++i)
      rhbuf[(size_t)(drow + i) * HH + dcol] = f2bf(rr[i] * h_loc[i]);

    tgt += GROUP_WGS;
    group_barrier(bar, tgt);

    // ================= phase 2: h_tilde, h_new =================
    float4v ah = {0.f, 0.f, 0.f, 0.f};
#pragma unroll
    for (int kx = 0; kx < 8; ++kx)
      ah = __builtin_amdgcn_mfma_f32_16x16x32_bf16(xf[kx], wh[16 + kx], ah, 0, 0, 0);
#pragma unroll
    for (int kk = 0; kk < 16; ++kk) {
      short8 a = *(const short8*)(rh_lane + kk * 32);
      ah = __builtin_amdgcn_mfma_f32_16x16x32_bf16(a, wh[kk], ah, 0, 0, 0);
    }

    // prefetch x for t+1 (latency hidden under barrier 2)
    if (t + 1 < TT) {
      const float* xl = x_lane0 + (size_t)(t + 1) * FF;
#pragma unroll
      for (int kx = 0; kx < 8; ++kx) {
        float4v a = *(const float4v*)(xl + kx * 32);
        float4v b2 = *(const float4v*)(xl + kx * 32 + 4);
        short8 v;
        v[0] = f2bf(a[0]); v[1] = f2bf(a[1]); v[2] = f2bf(a[2]); v[3] = f2bf(a[3]);
        v[4] = f2bf(b2[0]); v[5] = f2bf(b2[1]); v[6] = f2bf(b2[2]); v[7] = f2bf(b2[3]);
        xf[kx] = v;
      }
    }

#pragma unroll
    for (int i = 0; i < 4; ++i) {
      float hv = tanh_(ah[i] + bh);
      h_loc[i] = (1.0f - z[i]) * h_loc[i] + z[i] * hv;
    }
#pragma unroll
    for (int i = 0; i < 4; ++i)
      hbuf[(size_t)(drow + i) * HH + dcol] = f2bf(h_loc[i]);
    if (t == TT - 1) {
#pragma unroll
      for (int i = 0; i < 4; ++i)
        hfin[(size_t)(drow + i) * HH + dcol] = h_loc[i];
    }

    if (t + 1 < TT) {
      tgt += GROUP_WGS;
      group_barrier(bar, tgt);
    }
  }
}

// out[b, c] = h_final[b,:] @ fc_w[:,c] + fc_b[c]   (256x512 @ 512x10, f32)
__global__ void fc_kernel(const float* __restrict__ hfin, const float* __restrict__ fw,
                          const float* __restrict__ fb, float* __restrict__ out) {
  int b = blockIdx.x;
  int tid = threadIdx.x;  // 64 (one wave)
  float p[10];
#pragma unroll
  for (int c = 0; c < 10; ++c) p[c] = 0.f;
  for (int k = tid; k < HH; k += 64) {
    float hv = hfin[(size_t)b * HH + k];
#pragma unroll
    for (int c = 0; c < 10; ++c) p[c] += hv * fw[k * 10 + c];
  }
#pragma unroll
  for (int c = 0; c < 10; ++c) {
    float v = p[c];
    for (int off = 32; off > 0; off >>= 1) v += __shfl_down(v, off);
    if (tid == 0) out[b * 10 + c] = v + fb[c];
  }
}

extern "C" void kernel_launch(void* const* d_in, const int* in_sizes, int n_in,
                              void* d_out, int out_size, void* d_ws, size_t ws_size,
                              hipStream_t stream) {
  const float* x = (const float*)d_in[0];
  const float* Wz_w = (const float*)d_in[1];
  const float* Wz_b = (const float*)d_in[2];
  const float* Wr_w = (const float*)d_in[3];
  const float* Wr_b = (const float*)d_in[4];
  const float* Wh_w = (const float*)d_in[5];
  const float* Wh_b = (const float*)d_in[6];
  const float* fc_w = (const float*)d_in[7];
  const float* fc_b = (const float*)d_in[8];

  char* ws = (char*)d_ws;
  short* wfrag = (short*)(ws + WFRAG_OFF);
  short* hbuf = (short*)(ws + HBUF_OFF);
  short* rhbuf = (short*)(ws + RHBUF_OFF);
  float* hfin = (float*)(ws + HFIN_OFF);
  int* bars = (int*)(ws + BAR_OFF);

  // h0 = 0 and barrier counters = 0 (must be reset on EVERY launch)
  hipMemsetAsync(hbuf, 0, BB * HH * 2, stream);
  hipMemsetAsync(bars, 0, 1024, stream);

  prep_w<<<576, 256, 0, stream>>>(Wz_w, Wr_w, Wh_w, wfrag);
  gru_kernel<<<128, 256, 0, stream>>>(x, wfrag, hbuf, rhbuf, hfin, bars,
                                      Wz_b, Wr_b, Wh_b);
  fc_kernel<<<BB, 64, 0, stream>>>(hfin, fc_w, fc_b, (float*)d_out);
}

// Round 2
// 15828.876 us; speedup vs baseline: 1.9955x; 1.9955x over previous
//
#include <hip/hip_runtime.h>

// GRU: B=256, T=512, F=256, H=512, C=10  (MI355X / gfx950)
// Persistent-style kernel, 128 WGs x 256 thr.
// 16 row-groups x 16 rows; each group = 8 WGs covering 512 cols (WG: 16r x 64c,
// wave: 16r x 16c). Weights live in registers (AGPR) as MFMA B-fragments.
// Cross-WG h / r*h exchange via global + LIC-coherent relaxed atomics:
//   arrive: release fence (wbl2) + relaxed system fetch_add   (one per WG)
//   wait:   relaxed system polls (NO per-poll L2 invalidate) + one acquire fence
// x is pre-converted to bf16 (xprep) when ws_size allows.

#define BB 256
#define TT 512
#define FF 256
#define HH 512
#define NGROUP 16
#define GROUP_WGS 8

typedef short short8 __attribute__((ext_vector_type(8)));
typedef float float4v __attribute__((ext_vector_type(4)));

// ws layout (bytes)
#define WFRAG_OFF 0
#define WFRAG_BYTES (32 * 3 * 24 * 64 * 8 * 2)            // 2,359,296
#define HBUF_OFF (WFRAG_OFF + WFRAG_BYTES)                 // bf16 h   [256][512]
#define RHBUF_OFF (HBUF_OFF + BB * HH * 2)                 // bf16 r*h [256][512]
#define HFIN_OFF (RHBUF_OFF + BB * HH * 2)                 // f32 h_final [256][512]
#define BAR_OFF (HFIN_OFF + BB * HH * 4)                   // 16 x 256B counters
#define XB_OFF (BAR_OFF + 4096)                            // bf16 x [256][512][256]
#define XB_BYTES ((size_t)BB * TT * FF * 2)
#define WS_XB_NEEDED ((size_t)XB_OFF + XB_BYTES)

__device__ __forceinline__ short f2bf(float f) {
  unsigned u = __builtin_bit_cast(unsigned, f);
  u += 0x7fffu + ((u >> 16) & 1u);            // RNE to bf16 (no NaN in data)
  return (short)(u >> 16);
}
__device__ __forceinline__ float sigm(float v) { return 1.0f / (1.0f + __expf(-v)); }
__device__ __forceinline__ float tanh_(float v) { return 2.0f / (1.0f + __expf(-2.0f * v)) - 1.0f; }

// ---- weight prep: f32 [768][512] -> bf16 MFMA B-fragments ----
// Frag (cb, g, kk, lane, j): n = cb*16 + (lane&15), k = kk*32 + (lane>>4)*8 + j.
__global__ void prep_w(const float* __restrict__ Wz, const float* __restrict__ Wr,
                       const float* __restrict__ Wh, short* __restrict__ wfrag) {
  int id = blockIdx.x * 256 + threadIdx.x;     // 576*256 == 32*3*24*64
  int lane = id & 63;
  int rest = id >> 6;                          // (cb*3+g)*24 + kk
  int kk = rest % 24;
  int gc = rest / 24;
  int g = gc % 3;
  int cb = gc / 3;
  if (cb >= 32) return;
  const float* W = (g == 0) ? Wz : ((g == 1) ? Wr : Wh);
  int n = cb * 16 + (lane & 15);
  int kbase = kk * 32 + (lane >> 4) * 8;
  short8 v;
#pragma unroll
  for (int j = 0; j < 8; ++j) v[j] = f2bf(W[(size_t)(kbase + j) * HH + n]);
  *(((short8*)wfrag) + id) = v;
}

// ---- x prep: f32 -> bf16 (same [b][t][f] layout) ----
__global__ void xprep(const float* __restrict__ x, short* __restrict__ xb) {
  size_t i = (size_t)blockIdx.x * 256 + threadIdx.x;   // one short8 per thread
  const float4v* src = (const float4v*)x;
  float4v a = src[i * 2], b = src[i * 2 + 1];
  short8 v;
  v[0] = f2bf(a[0]); v[1] = f2bf(a[1]); v[2] = f2bf(a[2]); v[3] = f2bf(a[3]);
  v[4] = f2bf(b[0]); v[5] = f2bf(b[1]); v[6] = f2bf(b[2]); v[7] = f2bf(b[3]);
  *(((short8*)xb) + i) = v;
}

// ---- barrier: arrive / wait split, relaxed polls, single fences ----
__device__ __forceinline__ void bar_arrive(int* bar) {
  __builtin_amdgcn_fence(__ATOMIC_RELEASE, "agent");   // vmcnt drain + buffer_wbl2
  __syncthreads();                                      // all waves' stores flushed
  if (threadIdx.x == 0)
    __hip_atomic_fetch_add(bar, 1, __ATOMIC_RELAXED, __HIP_MEMORY_SCOPE_SYSTEM);
}
__device__ __forceinline__ void bar_wait(int* bar, int tgt) {
  if (threadIdx.x == 0) {
    while (__hip_atomic_load(bar, __ATOMIC_RELAXED, __HIP_MEMORY_SCOPE_SYSTEM) < tgt)
      __builtin_amdgcn_s_sleep(1);
  }
  __syncthreads();
  __builtin_amdgcn_fence(__ATOMIC_ACQUIRE, "agent");   // one buffer_inv
}

template <bool XB>
__global__ __launch_bounds__(256, 1) void gru_kernel(
    const void* __restrict__ xv, const short* __restrict__ wfrag,
    short* __restrict__ hbuf, short* __restrict__ rhbuf,
    float* __restrict__ hfin, int* __restrict__ bars,
    const float* __restrict__ bzv, const float* __restrict__ brv,
    const float* __restrict__ bhv) {
  const int bid = blockIdx.x;          // 0..127
  const int xcdi = bid & 7;            // blockIdx%8 ~ XCD round-robin (speed only)
  const int idx = bid >> 3;            // 0..15 within XCD
  const int group = xcdi * 2 + (idx >> 3);   // 0..15 (group's 8 WGs share an XCD)
  const int member = idx & 7;          // 0..7 -> 64-col block
  const int tid = threadIdx.x;
  const int w = tid >> 6;              // wave 0..3 -> 16-col sub-block
  const int l = tid & 63;
  const int l15 = l & 15;
  const int lhi = l >> 4;
  const int rb = group * 16;           // 16 batch rows per group
  const int cbg = member * 4 + w;      // global 16-col block 0..31
  const int jc = cbg * 16;

  // ---- weights -> registers (B-fragments) ----
  const short8* wf = (const short8*)wfrag;
  short8 wz[24], wr[24], wh[24];
#pragma unroll
  for (int kk = 0; kk < 24; ++kk) wz[kk] = wf[((cbg * 3 + 0) * 24 + kk) * 64 + l];
#pragma unroll
  for (int kk = 0; kk < 24; ++kk) wr[kk] = wf[((cbg * 3 + 1) * 24 + kk) * 64 + l];
#pragma unroll
  for (int kk = 0; kk < 24; ++kk) wh[kk] = wf[((cbg * 3 + 2) * 24 + kk) * 64 + l];

  const float bz = bzv[jc + l15], br = brv[jc + l15], bh = bhv[jc + l15];

  const int arow = rb + l15;           // A-fragment row (same 16 rows for all waves)
  const int drow = rb + lhi * 4;       // D rows base (+i)
  const int dcol = jc + l15;

  const short* hb_lane = hbuf + (size_t)arow * HH + lhi * 8;
  const short* rh_lane = rhbuf + (size_t)arow * HH + lhi * 8;
  const float* xf32 = XB ? nullptr : ((const float*)xv + (size_t)arow * TT * FF + lhi * 8);
  const short* xb16 = XB ? ((const short*)xv + (size_t)arow * TT * FF + lhi * 8) : nullptr;

  // h_loc holds h[drow+i][dcol] (the 4 output elems this lane owns)
  float4v h_loc = {0.f, 0.f, 0.f, 0.f};
  int tgt = 0;
  int* bar = bars + group * 64;

  // ---- prefetch x fragments for t=0, prime z/r x-contributions ----
  short8 xf[8];
#pragma unroll
  for (int kx = 0; kx < 8; ++kx) {
    if (XB) {
      xf[kx] = *(const short8*)(xb16 + kx * 32);
    } else {
      float4v a = *(const float4v*)(xf32 + kx * 32);
      float4v b2 = *(const float4v*)(xf32 + kx * 32 + 4);
      short8 v;
      v[0] = f2bf(a[0]); v[1] = f2bf(a[1]); v[2] = f2bf(a[2]); v[3] = f2bf(a[3]);
      v[4] = f2bf(b2[0]); v[5] = f2bf(b2[1]); v[6] = f2bf(b2[2]); v[7] = f2bf(b2[3]);
      xf[kx] = v;
    }
  }
  float4v azx = {0.f, 0.f, 0.f, 0.f}, arx = {0.f, 0.f, 0.f, 0.f};
#pragma unroll
  for (int kx = 0; kx < 8; ++kx) {
    azx = __builtin_amdgcn_mfma_f32_16x16x32_bf16(xf[kx], wz[16 + kx], azx, 0, 0, 0);
    arx = __builtin_amdgcn_mfma_f32_16x16x32_bf16(xf[kx], wr[16 + kx], arx, 0, 0, 0);
  }

#pragma unroll 1
  for (int t = 0; t < TT; ++t) {
    // ================= phase 1: z, r =================
    float4v az = azx, ar = arx;
#pragma unroll
    for (int kk = 0; kk < 16; ++kk) {  // h part (K=512)
      short8 a = *(const short8*)(hb_lane + kk * 32);
      az = __builtin_amdgcn_mfma_f32_16x16x32_bf16(a, wz[kk], az, 0, 0, 0);
      ar = __builtin_amdgcn_mfma_f32_16x16x32_bf16(a, wr[kk], ar, 0, 0, 0);
    }
    float4v z, rr;
#pragma unroll
    for (int i = 0; i < 4; ++i) {
      z[i] = sigm(az[i] + bz);
      rr[i] = sigm(ar[i] + br);
    }
#pragma unroll
    for (int i = 0; i < 4; ++i)
      rhbuf[(size_t)(drow + i) * HH + dcol] = f2bf(rr[i] * h_loc[i]);

    tgt += GROUP_WGS;
    bar_arrive(bar);
    // overlap: h_tilde x-contribution while barrier settles
    float4v ah = {0.f, 0.f, 0.f, 0.f};
#pragma unroll
    for (int kx = 0; kx < 8; ++kx)
      ah = __builtin_amdgcn_mfma_f32_16x16x32_bf16(xf[kx], wh[16 + kx], ah, 0, 0, 0);
    bar_wait(bar, tgt);

    // ================= phase 2: h_tilde, h_new =================
#pragma unroll
    for (int kk = 0; kk < 16; ++kk) {
      short8 a = *(const short8*)(rh_lane + kk * 32);
      ah = __builtin_amdgcn_mfma_f32_16x16x32_bf16(a, wh[kk], ah, 0, 0, 0);
    }

    // prefetch x for t+1 (completes under barrier 2)
    if (t + 1 < TT) {
#pragma unroll
      for (int kx = 0; kx < 8; ++kx) {
        if (XB) {
          xf[kx] = *(const short8*)(xb16 + (size_t)(t + 1) * FF + kx * 32);
        } else {
          const float* xl = xf32 + (size_t)(t + 1) * FF;
          float4v a = *(const float4v*)(xl + kx * 32);
          float4v b2 = *(const float4v*)(xl + kx * 32 + 4);
          short8 v;
          v[0] = f2bf(a[0]); v[1] = f2bf(a[1]); v[2] = f2bf(a[2]); v[3] = f2bf(a[3]);
          v[4] = f2bf(b2[0]); v[5] = f2bf(b2[1]); v[6] = f2bf(b2[2]); v[7] = f2bf(b2[3]);
          xf[kx] = v;
        }
      }
    }

#pragma unroll
    for (int i = 0; i < 4; ++i) {
      float hv = tanh_(ah[i] + bh);
      h_loc[i] = (1.0f - z[i]) * h_loc[i] + z[i] * hv;
    }
#pragma unroll
    for (int i = 0; i < 4; ++i)
      hbuf[(size_t)(drow + i) * HH + dcol] = f2bf(h_loc[i]);
    if (t == TT - 1) {
#pragma unroll
      for (int i = 0; i < 4; ++i)
        hfin[(size_t)(drow + i) * HH + dcol] = h_loc[i];
    }

    if (t + 1 < TT) {
      tgt += GROUP_WGS;
      bar_arrive(bar);
      // overlap: next step's z/r x-contributions while barrier settles
      azx = (float4v){0.f, 0.f, 0.f, 0.f};
      arx = (float4v){0.f, 0.f, 0.f, 0.f};
#pragma unroll
      for (int kx = 0; kx < 8; ++kx) {
        azx = __builtin_amdgcn_mfma_f32_16x16x32_bf16(xf[kx], wz[16 + kx], azx, 0, 0, 0);
        arx = __builtin_amdgcn_mfma_f32_16x16x32_bf16(xf[kx], wr[16 + kx], arx, 0, 0, 0);
      }
      bar_wait(bar, tgt);
    }
  }
}

// out[b, c] = h_final[b,:] @ fc_w[:,c] + fc_b[c]   (256x512 @ 512x10, f32)
__global__ void fc_kernel(const float* __restrict__ hfin, const float* __restrict__ fw,
                          const float* __restrict__ fb, float* __restrict__ out) {
  int b = blockIdx.x;
  int tid = threadIdx.x;  // 64 (one wave)
  float p[10];
#pragma unroll
  for (int c = 0; c < 10; ++c) p[c] = 0.f;
  for (int k = tid; k < HH; k += 64) {
    float hv = hfin[(size_t)b * HH + k];
#pragma unroll
    for (int c = 0; c < 10; ++c) p[c] += hv * fw[k * 10 + c];
  }
#pragma unroll
  for (int c = 0; c < 10; ++c) {
    float v = p[c];
    for (int off = 32; off > 0; off >>= 1) v += __shfl_down(v, off);
    if (tid == 0) out[b * 10 + c] = v + fb[c];
  }
}

extern "C" void kernel_launch(void* const* d_in, const int* in_sizes, int n_in,
                              void* d_out, int out_size, void* d_ws, size_t ws_size,
                              hipStream_t stream) {
  const float* x = (const float*)d_in[0];
  const float* Wz_w = (const float*)d_in[1];
  const float* Wz_b = (const float*)d_in[2];
  const float* Wr_w = (const float*)d_in[3];
  const float* Wr_b = (const float*)d_in[4];
  const float* Wh_w = (const float*)d_in[5];
  const float* Wh_b = (const float*)d_in[6];
  const float* fc_w = (const float*)d_in[7];
  const float* fc_b = (const float*)d_in[8];

  char* ws = (char*)d_ws;
  short* wfrag = (short*)(ws + WFRAG_OFF);
  short* hbuf = (short*)(ws + HBUF_OFF);
  short* rhbuf = (short*)(ws + RHBUF_OFF);
  float* hfin = (float*)(ws + HFIN_OFF);
  int* bars = (int*)(ws + BAR_OFF);
  short* xb = (short*)(ws + XB_OFF);

  // h0 = 0 and barrier counters = 0 (must be reset on EVERY launch)
  hipMemsetAsync(hbuf, 0, BB * HH * 2, stream);
  hipMemsetAsync(bars, 0, 4096, stream);

  prep_w<<<576, 256, 0, stream>>>(Wz_w, Wr_w, Wh_w, wfrag);

  if (ws_size >= WS_XB_NEEDED) {
    xprep<<<(BB * TT * FF / 8) / 256, 256, 0, stream>>>(x, xb);
    gru_kernel<true><<<128, 256, 0, stream>>>(xb, wfrag, hbuf, rhbuf, hfin, bars,
                                              Wz_b, Wr_b, Wh_b);
  } else {
    gru_kernel<false><<<128, 256, 0, stream>>>(x, wfrag, hbuf, rhbuf, hfin, bars,
                                               Wz_b, Wr_b, Wh_b);
  }
  fc_kernel<<<BB, 64, 0, stream>>>(hfin, fc_w, fc_b, (float*)d_out);
}

// Round 3
// 4998.018 us; speedup vs baseline: 6.3197x; 3.1670x over previous
//
#include <hip/hip_runtime.h>

// GRU: B=256, T=512, F=256, H=512, C=10  (MI355X / gfx950)
// XCD-local persistent kernel:
//  - grid 256 WGs x 256 thr (1 WG/CU at this VGPR count). Each WG reads its
//    XCC_ID and claims a (group,member) slot in its OWN XCD; surplus exits.
//  - 16 groups (2 per XCD) x 16 batch rows; group = 8 WGs x 64 cols
//    (4 waves x 16 cols). Weights in registers as MFMA B-fragments.
//  - h / r*h exchange stays inside the XCD's L2: plain stores + vmcnt(0),
//    sc0 (L1-bypass) loads, and an L2-resident workgroup-scope atomic counter.
//    NO wbl2 / NO buffer_inv anywhere in the hot loop.

#define BB 256
#define TT 512
#define FF 256
#define HH 512
#define GROUP_WGS 8

typedef short short8 __attribute__((ext_vector_type(8)));
typedef short short4v __attribute__((ext_vector_type(4)));
typedef float float4v __attribute__((ext_vector_type(4)));
typedef unsigned long long u64;

// ws layout (bytes)
#define WFRAG_OFF 0
#define WFRAG_BYTES (32 * 3 * 24 * 64 * 8 * 2)            // 2,359,296
#define HBUF_OFF (WFRAG_OFF + WFRAG_BYTES)                 // bf16 h   [256][512]
#define RHBUF_OFF (HBUF_OFF + BB * HH * 2)                 // bf16 r*h [256][512]
#define HFIN_OFF (RHBUF_OFF + BB * HH * 2)                 // f32 h_final [256][512]
#define CTRL_OFF (HFIN_OFF + BB * HH * 4)                  // claim[8] + bars[16], 64B apart
#define CTRL_BYTES 4096
#define XB_OFF (CTRL_OFF + CTRL_BYTES)                     // bf16 x [256][512][256]
#define XB_BYTES ((size_t)BB * TT * FF * 2)
#define WS_XB_NEEDED ((size_t)XB_OFF + XB_BYTES)

__device__ __forceinline__ short f2bf(float f) {
  unsigned u = __builtin_bit_cast(unsigned, f);
  u += 0x7fffu + ((u >> 16) & 1u);            // RNE to bf16 (no NaN in data)
  return (short)(u >> 16);
}
__device__ __forceinline__ float sigm(float v) { return 1.0f / (1.0f + __expf(-v)); }
__device__ __forceinline__ float tanh_(float v) { return 2.0f / (1.0f + __expf(-2.0f * v)) - 1.0f; }

// ---- weight prep: f32 [768][512] -> bf16 MFMA B-fragments ----
__global__ void prep_w(const float* __restrict__ Wz, const float* __restrict__ Wr,
                       const float* __restrict__ Wh, short* __restrict__ wfrag) {
  int id = blockIdx.x * 256 + threadIdx.x;     // 576*256 == 32*3*24*64
  int lane = id & 63;
  int rest = id >> 6;
  int kk = rest % 24;
  int gc = rest / 24;
  int g = gc % 3;
  int cb = gc / 3;
  if (cb >= 32) return;
  const float* W = (g == 0) ? Wz : ((g == 1) ? Wr : Wh);
  int n = cb * 16 + (lane & 15);
  int kbase = kk * 32 + (lane >> 4) * 8;
  short8 v;
#pragma unroll
  for (int j = 0; j < 8; ++j) v[j] = f2bf(W[(size_t)(kbase + j) * HH + n]);
  *(((short8*)wfrag) + id) = v;
}

// ---- x prep: f32 -> bf16 ----
__global__ void xprep(const float* __restrict__ x, short* __restrict__ xb) {
  size_t i = (size_t)blockIdx.x * 256 + threadIdx.x;
  const float4v* src = (const float4v*)x;
  float4v a = src[i * 2], b = src[i * 2 + 1];
  short8 v;
  v[0] = f2bf(a[0]); v[1] = f2bf(a[1]); v[2] = f2bf(a[2]); v[3] = f2bf(a[3]);
  v[4] = f2bf(b[0]); v[5] = f2bf(b[1]); v[6] = f2bf(b[2]); v[7] = f2bf(b[3]);
  *(((short8*)xb) + i) = v;
}

// ---- XCD-local barrier: no cache maintenance ----
__device__ __forceinline__ void bar_arrive(int* bar) {
  asm volatile("s_waitcnt vmcnt(0)" ::: "memory");  // our stores are in XCD L2
  __syncthreads();                                  // all 4 waves done
  if (threadIdx.x == 0)                             // L2-executed atomic (no sc bits)
    __hip_atomic_fetch_add(bar, 1, __ATOMIC_RELAXED, __HIP_MEMORY_SCOPE_WORKGROUP);
}
__device__ __forceinline__ void bar_wait(int* bar, int tgt) {
  if (threadIdx.x == 0) {
    while (__hip_atomic_load(bar, __ATOMIC_RELAXED, __HIP_MEMORY_SCOPE_AGENT) < tgt) {}
  }
  __syncthreads();
}

// sc0 (L1-bypass) 16B fragment load from XCD L2
__device__ __forceinline__ short8 ld_frag(const short* p) {
  const u64* q = (const u64*)p;
  u64 lo = __hip_atomic_load(q, __ATOMIC_RELAXED, __HIP_MEMORY_SCOPE_AGENT);
  u64 hi = __hip_atomic_load(q + 1, __ATOMIC_RELAXED, __HIP_MEMORY_SCOPE_AGENT);
  short4v l4 = __builtin_bit_cast(short4v, lo);
  short4v h4 = __builtin_bit_cast(short4v, hi);
  return __builtin_shufflevector(l4, h4, 0, 1, 2, 3, 4, 5, 6, 7);
}

template <bool XB>
__global__ __launch_bounds__(256, 1) void gru_kernel(
    const void* __restrict__ xv, const short* __restrict__ wfrag,
    short* __restrict__ hbuf, short* __restrict__ rhbuf,
    float* __restrict__ hfin, int* __restrict__ ctrl,
    const float* __restrict__ bzv, const float* __restrict__ brv,
    const float* __restrict__ bhv) {
  // ---- claim a slot in this XCD ----
  __shared__ int s_slot, s_xcc;
  if (threadIdx.x == 0) {
    unsigned xcc;
    asm volatile("s_getreg_b32 %0, hwreg(HW_REG_XCC_ID)" : "=s"(xcc));
    xcc &= 7u;
    s_xcc = (int)xcc;
    s_slot = atomicAdd(ctrl + xcc * 16, 1);   // device-scope claim
  }
  __syncthreads();
  const int slot = s_slot;
  if (slot >= 16) return;                      // surplus WG
  const int group = s_xcc * 2 + (slot >> 3);   // 0..15, both halves same XCD
  const int member = slot & 7;                 // 0..7 -> 64-col block

  const int tid = threadIdx.x;
  const int w = tid >> 6;
  const int l = tid & 63;
  const int l15 = l & 15;
  const int lhi = l >> 4;
  const int rb = group * 16;
  const int cbg = member * 4 + w;              // 16-col block 0..31
  const int jc = cbg * 16;

  // ---- weights -> registers ----
  const short8* wf = (const short8*)wfrag;
  short8 wz[24], wr[24], wh[24];
#pragma unroll
  for (int kk = 0; kk < 24; ++kk) wz[kk] = wf[((cbg * 3 + 0) * 24 + kk) * 64 + l];
#pragma unroll
  for (int kk = 0; kk < 24; ++kk) wr[kk] = wf[((cbg * 3 + 1) * 24 + kk) * 64 + l];
#pragma unroll
  for (int kk = 0; kk < 24; ++kk) wh[kk] = wf[((cbg * 3 + 2) * 24 + kk) * 64 + l];

  const float bz = bzv[jc + l15], br = brv[jc + l15], bh = bhv[jc + l15];

  const int arow = rb + l15;
  const int drow = rb + lhi * 4;
  const int dcol = jc + l15;

  const short* hb_lane = hbuf + (size_t)arow * HH + lhi * 8;
  const short* rh_lane = rhbuf + (size_t)arow * HH + lhi * 8;
  const float* xf32 = XB ? nullptr : ((const float*)xv + (size_t)arow * TT * FF + lhi * 8);
  const short* xb16 = XB ? ((const short*)xv + (size_t)arow * TT * FF + lhi * 8) : nullptr;

  float4v h_loc = {0.f, 0.f, 0.f, 0.f};
  int tgt = 0;
  int* bar = ctrl + 128 + group * 16;          // 64B line per group

  // ---- x fragments for t=0 + prime z/r x-contributions ----
  short8 xf[8];
#pragma unroll
  for (int kx = 0; kx < 8; ++kx) {
    if (XB) {
      xf[kx] = *(const short8*)(xb16 + kx * 32);
    } else {
      float4v a = *(const float4v*)(xf32 + kx * 32);
      float4v b2 = *(const float4v*)(xf32 + kx * 32 + 4);
      short8 v;
      v[0] = f2bf(a[0]); v[1] = f2bf(a[1]); v[2] = f2bf(a[2]); v[3] = f2bf(a[3]);
      v[4] = f2bf(b2[0]); v[5] = f2bf(b2[1]); v[6] = f2bf(b2[2]); v[7] = f2bf(b2[3]);
      xf[kx] = v;
    }
  }
  float4v azx = {0.f, 0.f, 0.f, 0.f}, arx = {0.f, 0.f, 0.f, 0.f};
#pragma unroll
  for (int kx = 0; kx < 8; ++kx) {
    azx = __builtin_amdgcn_mfma_f32_16x16x32_bf16(xf[kx], wz[16 + kx], azx, 0, 0, 0);
    arx = __builtin_amdgcn_mfma_f32_16x16x32_bf16(xf[kx], wr[16 + kx], arx, 0, 0, 0);
  }

#pragma unroll 1
  for (int t = 0; t < TT; ++t) {
    // ===== phase 1: z, r =====
    float4v az = azx, ar = arx;
#pragma unroll
    for (int kk = 0; kk < 16; ++kk) {
      short8 a = ld_frag(hb_lane + kk * 32);
      az = __builtin_amdgcn_mfma_f32_16x16x32_bf16(a, wz[kk], az, 0, 0, 0);
      ar = __builtin_amdgcn_mfma_f32_16x16x32_bf16(a, wr[kk], ar, 0, 0, 0);
    }
    float4v z, rr;
#pragma unroll
    for (int i = 0; i < 4; ++i) {
      z[i] = sigm(az[i] + bz);
      rr[i] = sigm(ar[i] + br);
    }
#pragma unroll
    for (int i = 0; i < 4; ++i)
      rhbuf[(size_t)(drow + i) * HH + dcol] = f2bf(rr[i] * h_loc[i]);

    tgt += GROUP_WGS;
    bar_arrive(bar);
    // overlap: h_tilde x-contribution while barrier settles
    float4v ah = {0.f, 0.f, 0.f, 0.f};
#pragma unroll
    for (int kx = 0; kx < 8; ++kx)
      ah = __builtin_amdgcn_mfma_f32_16x16x32_bf16(xf[kx], wh[16 + kx], ah, 0, 0, 0);
    bar_wait(bar, tgt);

    // ===== phase 2: h_tilde, h_new =====
#pragma unroll
    for (int kk = 0; kk < 16; ++kk) {
      short8 a = ld_frag(rh_lane + kk * 32);
      ah = __builtin_amdgcn_mfma_f32_16x16x32_bf16(a, wh[kk], ah, 0, 0, 0);
    }

    // prefetch x for t+1
    if (t + 1 < TT) {
#pragma unroll
      for (int kx = 0; kx < 8; ++kx) {
        if (XB) {
          xf[kx] = *(const short8*)(xb16 + (size_t)(t + 1) * FF + kx * 32);
        } else {
          const float* xl = xf32 + (size_t)(t + 1) * FF;
          float4v a = *(const float4v*)(xl + kx * 32);
          float4v b2 = *(const float4v*)(xl + kx * 32 + 4);
          short8 v;
          v[0] = f2bf(a[0]); v[1] = f2bf(a[1]); v[2] = f2bf(a[2]); v[3] = f2bf(a[3]);
          v[4] = f2bf(b2[0]); v[5] = f2bf(b2[1]); v[6] = f2bf(b2[2]); v[7] = f2bf(b2[3]);
          xf[kx] = v;
        }
      }
    }

#pragma unroll
    for (int i = 0; i < 4; ++i) {
      float hv = tanh_(ah[i] + bh);
      h_loc[i] = (1.0f - z[i]) * h_loc[i] + z[i] * hv;
    }

    if (t + 1 < TT) {
#pragma unroll
      for (int i = 0; i < 4; ++i)
        hbuf[(size_t)(drow + i) * HH + dcol] = f2bf(h_loc[i]);
      tgt += GROUP_WGS;
      bar_arrive(bar);
      // overlap: next step's z/r x-contributions
      azx = (float4v){0.f, 0.f, 0.f, 0.f};
      arx = (float4v){0.f, 0.f, 0.f, 0.f};
#pragma unroll
      for (int kx = 0; kx < 8; ++kx) {
        azx = __builtin_amdgcn_mfma_f32_16x16x32_bf16(xf[kx], wz[16 + kx], azx, 0, 0, 0);
        arx = __builtin_amdgcn_mfma_f32_16x16x32_bf16(xf[kx], wr[16 + kx], arx, 0, 0, 0);
      }
      bar_wait(bar, tgt);
    } else {
#pragma unroll
      for (int i = 0; i < 4; ++i)
        hfin[(size_t)(drow + i) * HH + dcol] = h_loc[i];
    }
  }
}

// out[b, c] = h_final[b,:] @ fc_w[:,c] + fc_b[c]
__global__ void fc_kernel(const float* __restrict__ hfin, const float* __restrict__ fw,
                          const float* __restrict__ fb, float* __restrict__ out) {
  int b = blockIdx.x;
  int tid = threadIdx.x;  // 64
  float p[10];
#pragma unroll
  for (int c = 0; c < 10; ++c) p[c] = 0.f;
  for (int k = tid; k < HH; k += 64) {
    float hv = hfin[(size_t)b * HH + k];
#pragma unroll
    for (int c = 0; c < 10; ++c) p[c] += hv * fw[k * 10 + c];
  }
#pragma unroll
  for (int c = 0; c < 10; ++c) {
    float v = p[c];
    for (int off = 32; off > 0; off >>= 1) v += __shfl_down(v, off);
    if (tid == 0) out[b * 10 + c] = v + fb[c];
  }
}

extern "C" void kernel_launch(void* const* d_in, const int* in_sizes, int n_in,
                              void* d_out, int out_size, void* d_ws, size_t ws_size,
                              hipStream_t stream) {
  const float* x = (const float*)d_in[0];
  const float* Wz_w = (const float*)d_in[1];
  const float* Wz_b = (const float*)d_in[2];
  const float* Wr_w = (const float*)d_in[3];
  const float* Wr_b = (const float*)d_in[4];
  const float* Wh_w = (const float*)d_in[5];
  const float* Wh_b = (const float*)d_in[6];
  const float* fc_w = (const float*)d_in[7];
  const float* fc_b = (const float*)d_in[8];

  char* ws = (char*)d_ws;
  short* wfrag = (short*)(ws + WFRAG_OFF);
  short* hbuf = (short*)(ws + HBUF_OFF);
  short* rhbuf = (short*)(ws + RHBUF_OFF);
  float* hfin = (float*)(ws + HFIN_OFF);
  int* ctrl = (int*)(ws + CTRL_OFF);
  short* xb = (short*)(ws + XB_OFF);

  // h0 = 0, claim counters = 0, barrier counters = 0 (EVERY launch)
  hipMemsetAsync(hbuf, 0, BB * HH * 2, stream);
  hipMemsetAsync(ctrl, 0, CTRL_BYTES, stream);

  prep_w<<<576, 256, 0, stream>>>(Wz_w, Wr_w, Wh_w, wfrag);

  if (ws_size >= WS_XB_NEEDED) {
    xprep<<<(BB * TT * FF / 8) / 256, 256, 0, stream>>>(x, xb);
    gru_kernel<true><<<256, 256, 0, stream>>>(xb, wfrag, hbuf, rhbuf, hfin, ctrl,
                                              Wz_b, Wr_b, Wh_b);
  } else {
    gru_kernel<false><<<256, 256, 0, stream>>>(x, wfrag, hbuf, rhbuf, hfin, ctrl,
                                               Wz_b, Wr_b, Wh_b);
  }
  fc_kernel<<<BB, 64, 0, stream>>>(hfin, fc_w, fc_b, (float*)d_out);
}